// Round 1
// 551.037 us; speedup vs baseline: 1.1876x; 1.1876x over previous
//
#include <hip/hip_runtime.h>

#define N_NODES 100000
#define E_EDGES 3200000
#define IN_F 128
#define ATT 128
#define HEADS 8
#define DK 16
#define SLOPE 0.2f
#define NH (N_NODES * HEADS)   // 800000

// Binning parameters
#define CHUNK 896
#define NBINS 112                 // 112*896 = 100352 >= N
#define NS 8                      // privatized denom copies / splits per bin
#define HB 512                    // hist/scatter blocks
#define EPB 6272                  // edges per hist/scatter block (mult of 4; 512*6272 >= E)

// ---------------------------------------------------------------------------
// K1: wx = x @ W   (100000x128 @ 128x128, fp32 vector FMA)
//     + fused epilogue: s_src[n][h] = sum_k wx[n][h*16+k]*a1[k], s_dst with a2
// ---------------------------------------------------------------------------
__global__ __launch_bounds__(256) void gemm_s_kernel(
    const float* __restrict__ x, const float* __restrict__ W,
    const float* __restrict__ a, float* __restrict__ wx,
    float* __restrict__ s_src, float* __restrict__ s_dst)
{
    __shared__ float xs[8][128];   // [k][row] transposed x tile
    __shared__ float Ws[8][128];   // [k][col]

    const int tid = threadIdx.x;
    const int ty  = tid >> 4;      // 0..15  -> row group (8 rows)
    const int tx  = tid & 15;      // 0..15  -> col group (8 cols)
    const int row0 = blockIdx.x * 128;

    float acc[8][8];
#pragma unroll
    for (int i = 0; i < 8; i++)
#pragma unroll
        for (int j = 0; j < 8; j++) acc[i][j] = 0.f;

    const int lrow  = tid >> 1;        // 0..127 row for x staging
    const int khalf = (tid & 1) * 4;   // 0 or 4
    const int wkk   = tid >> 5;        // 0..7 k-row for W staging
    const int wc    = (tid & 31) * 4;  // col*4

    for (int k0 = 0; k0 < IN_F; k0 += 8) {
        float4 xv = make_float4(0.f, 0.f, 0.f, 0.f);
        const int grow = row0 + lrow;
        if (grow < N_NODES)
            xv = *(const float4*)(x + (size_t)grow * IN_F + k0 + khalf);
        const float4 wv = *(const float4*)(W + (size_t)(k0 + wkk) * ATT + wc);

        __syncthreads();   // previous iter's reads done
        xs[khalf + 0][lrow] = xv.x;
        xs[khalf + 1][lrow] = xv.y;
        xs[khalf + 2][lrow] = xv.z;
        xs[khalf + 3][lrow] = xv.w;
        *(float4*)(&Ws[wkk][wc]) = wv;
        __syncthreads();

#pragma unroll
        for (int kk = 0; kk < 8; kk++) {
            float av[8], bv[8];
            *(float4*)(av)     = *(const float4*)(&xs[kk][ty * 8]);
            *(float4*)(av + 4) = *(const float4*)(&xs[kk][ty * 8 + 4]);
            *(float4*)(bv)     = *(const float4*)(&Ws[kk][tx * 8]);
            *(float4*)(bv + 4) = *(const float4*)(&Ws[kk][tx * 8 + 4]);
#pragma unroll
            for (int r = 0; r < 8; r++)
#pragma unroll
                for (int c = 0; c < 8; c++)
                    acc[r][c] = fmaf(av[r], bv[c], acc[r][c]);
        }
    }

    const int koff = (tx & 1) * 8;
    const int head = tx >> 1;
    float a1[8], a2[8];
#pragma unroll
    for (int c = 0; c < 8; c++) {
        a1[c] = a[koff + c];
        a2[c] = a[DK + koff + c];
    }

#pragma unroll
    for (int r = 0; r < 8; r++) {
        const int grow = row0 + ty * 8 + r;
        const bool ok = (grow < N_NODES);
        if (ok) {
            *(float4*)(wx + (size_t)grow * ATT + tx * 8) =
                make_float4(acc[r][0], acc[r][1], acc[r][2], acc[r][3]);
            *(float4*)(wx + (size_t)grow * ATT + tx * 8 + 4) =
                make_float4(acc[r][4], acc[r][5], acc[r][6], acc[r][7]);
        }
        float p1 = 0.f, p2 = 0.f;
#pragma unroll
        for (int c = 0; c < 8; c++) {
            p1 = fmaf(acc[r][c], a1[c], p1);
            p2 = fmaf(acc[r][c], a2[c], p2);
        }
        p1 += __shfl_xor(p1, 1);
        p2 += __shfl_xor(p2, 1);
        if (((tx & 1) == 0) && ok) {
            s_src[(size_t)grow * HEADS + head] = p1;
            s_dst[(size_t)grow * HEADS + head] = p2;
        }
    }
}

// ---------------------------------------------------------------------------
// K2a: per-block histogram of src -> chunk bins. counts[c][b] layout
//      (chunk-major) so the prefix scan order is (c, b).
// ---------------------------------------------------------------------------
__global__ __launch_bounds__(256) void hist_kernel(
    const int* __restrict__ src, int* __restrict__ counts)
{
    __shared__ int h[NBINS];
    const int t = threadIdx.x;
    const int b = blockIdx.x;
    for (int i = t; i < NBINS; i += 256) h[i] = 0;
    __syncthreads();

    const int rb = b * EPB;
    const int re = min(rb + EPB, E_EDGES);
    for (int i = rb + t * 4; i < re; i += 256 * 4) {
        const int4 s4 = *(const int4*)(src + i);
        atomicAdd(&h[s4.x / CHUNK], 1);
        atomicAdd(&h[s4.y / CHUNK], 1);
        atomicAdd(&h[s4.z / CHUNK], 1);
        atomicAdd(&h[s4.w / CHUNK], 1);
    }
    __syncthreads();
    for (int i = t; i < NBINS; i += 256) counts[i * HB + b] = h[i];
}

// ---------------------------------------------------------------------------
// K2b: single-block exclusive prefix scan over counts[NBINS*HB] -> offs
// ---------------------------------------------------------------------------
__global__ __launch_bounds__(1024) void scan_kernel(
    const int* __restrict__ counts, int* __restrict__ offs)
{
    __shared__ int part[1024];
    const int t = threadIdx.x;
    const int per = (NBINS * HB) / 1024;   // 56
    const int base = t * per;

    int sum = 0;
    for (int i = 0; i < per; i++) sum += counts[base + i];
    part[t] = sum;
    __syncthreads();

    for (int off = 1; off < 1024; off <<= 1) {
        int v = 0;
        if (t >= off) v = part[t - off];
        __syncthreads();
        if (t >= off) part[t] += v;
        __syncthreads();
    }

    int run = (t == 0) ? 0 : part[t - 1];
    for (int i = 0; i < per; i++) {
        offs[base + i] = run;
        run += counts[base + i];
    }
}

// ---------------------------------------------------------------------------
// K2c: scatter edges into chunk bins. Packed word: (src - lo) << 17 | dst
//      (src-lo < 896 -> 10 bits, dst < 100000 -> 17 bits)
// ---------------------------------------------------------------------------
__global__ __launch_bounds__(256) void scatter_kernel(
    const int* __restrict__ src, const int* __restrict__ dst,
    const int* __restrict__ offs, unsigned int* __restrict__ binned)
{
    __shared__ int cur[NBINS];
    const int t = threadIdx.x;
    const int b = blockIdx.x;
    for (int i = t; i < NBINS; i += 256) cur[i] = offs[i * HB + b];
    __syncthreads();

    const int rb = b * EPB;
    const int re = min(rb + EPB, E_EDGES);
    for (int i = rb + t * 4; i < re; i += 256 * 4) {
        const int4 s4 = *(const int4*)(src + i);
        const int4 d4 = *(const int4*)(dst + i);
        const int ss[4] = {s4.x, s4.y, s4.z, s4.w};
        const int dd[4] = {d4.x, d4.y, d4.z, d4.w};
#pragma unroll
        for (int j = 0; j < 4; j++) {
            const int c = ss[j] / CHUNK;
            const int pos = atomicAdd(&cur[c], 1);
            binned[pos] = ((unsigned int)(ss[j] - c * CHUNK) << 17) |
                          (unsigned int)dd[j];
        }
    }
}

// ---------------------------------------------------------------------------
// K2d: dense per-bin denom accumulation. Block (c, j): process split j of
// chunk c's bin. Every lane does useful work; s_src slice (28 KB) is
// L1-resident, s_dst gathers hit L2. No global atomics.
// ---------------------------------------------------------------------------
__global__ __launch_bounds__(256, 4) void denom_binned_kernel(
    const unsigned int* __restrict__ binned, const int* __restrict__ offs,
    const float* __restrict__ s_src, const float* __restrict__ s_dst,
    float* __restrict__ denoms)   // [NS][NH]
{
    __shared__ float acc[HEADS][CHUNK + 1];   // 28704 B

    const int t  = threadIdx.x;
    const int c  = blockIdx.x;
    const int j  = blockIdx.y;
    const int lo = c * CHUNK;
    const int hi = min(lo + CHUNK, N_NODES);

    for (int i = t; i < HEADS * (CHUNK + 1); i += 256)
        ((float*)acc)[i] = 0.f;
    __syncthreads();

    const int start = offs[c * HB];
    const int end   = (c + 1 < NBINS) ? offs[(c + 1) * HB] : E_EDGES;
    const int len   = end - start;
    const int e0 = start + (int)((long long)len * j / NS);
    const int e1 = start + (int)((long long)len * (j + 1) / NS);

    int i = e0 + t;
    // pair-unrolled main loop: 2 independent gather chains in flight
    for (; i + 256 < e1; i += 512) {
        const unsigned int w0 = binned[i];
        const unsigned int w1 = binned[i + 256];
        const int di0 = w0 & 0x1FFFF, sl0 = w0 >> 17;
        const int di1 = w1 & 0x1FFFF, sl1 = w1 >> 17;
        const float4* ps0 = (const float4*)(s_src + (size_t)(lo + sl0) * HEADS);
        const float4* pd0 = (const float4*)(s_dst + (size_t)di0 * HEADS);
        const float4* ps1 = (const float4*)(s_src + (size_t)(lo + sl1) * HEADS);
        const float4* pd1 = (const float4*)(s_dst + (size_t)di1 * HEADS);
        const float4 xa0 = ps0[0], xa1 = ps0[1], xb0 = pd0[0], xb1 = pd0[1];
        const float4 ya0 = ps1[0], ya1 = ps1[1], yb0 = pd1[0], yb1 = pd1[1];
        const float s0[8] = {xa0.x + xb0.x, xa0.y + xb0.y, xa0.z + xb0.z, xa0.w + xb0.w,
                             xa1.x + xb1.x, xa1.y + xb1.y, xa1.z + xb1.z, xa1.w + xb1.w};
        const float s1[8] = {ya0.x + yb0.x, ya0.y + yb0.y, ya0.z + yb0.z, ya0.w + yb0.w,
                             ya1.x + yb1.x, ya1.y + yb1.y, ya1.z + yb1.z, ya1.w + yb1.w};
#pragma unroll
        for (int h = 0; h < 8; h++) {
            float v0 = s0[h]; v0 = v0 > 0.f ? v0 : SLOPE * v0;
            float v1 = s1[h]; v1 = v1 > 0.f ? v1 : SLOPE * v1;
            atomicAdd(&acc[h][sl0], __expf(v0));
            atomicAdd(&acc[h][sl1], __expf(v1));
        }
    }
    if (i < e1) {
        const unsigned int w0 = binned[i];
        const int di0 = w0 & 0x1FFFF, sl0 = w0 >> 17;
        const float4* ps0 = (const float4*)(s_src + (size_t)(lo + sl0) * HEADS);
        const float4* pd0 = (const float4*)(s_dst + (size_t)di0 * HEADS);
        const float4 xa0 = ps0[0], xa1 = ps0[1], xb0 = pd0[0], xb1 = pd0[1];
        const float s0[8] = {xa0.x + xb0.x, xa0.y + xb0.y, xa0.z + xb0.z, xa0.w + xb0.w,
                             xa1.x + xb1.x, xa1.y + xb1.y, xa1.z + xb1.z, xa1.w + xb1.w};
#pragma unroll
        for (int h = 0; h < 8; h++) {
            float v0 = s0[h]; v0 = v0 > 0.f ? v0 : SLOPE * v0;
            atomicAdd(&acc[h][sl0], __expf(v0));
        }
    }
    __syncthreads();

    // flush: transpose LDS head-major -> global node-major private copy
    const int cnt = (hi - lo) * HEADS;
    float* outp = denoms + (size_t)j * NH + (size_t)lo * HEADS;
    for (int i2 = t; i2 < cnt; i2 += 256)
        outp[i2] = acc[i2 & 7][i2 >> 3];
}

// ---------------------------------------------------------------------------
// K2e: rdenom[i] = 1 / sum_c denoms[c][i]  (written into copy 0)
// ---------------------------------------------------------------------------
__global__ __launch_bounds__(256) void reduce_recip_kernel(float* __restrict__ denoms)
{
    const int i = blockIdx.x * 256 + threadIdx.x;
    if (i >= NH) return;
    float s = 0.f;
#pragma unroll
    for (int c = 0; c < NS; c++) s += denoms[(size_t)c * NH + i];
    denoms[i] = __frcp_rn(s);
}

// ---------------------------------------------------------------------------
// K3: attention[e][h] = exp(leakyrelu(score)) * rdenom[src][h]
// ---------------------------------------------------------------------------
__global__ __launch_bounds__(256) void norm_kernel(
    const int* __restrict__ src, const int* __restrict__ dst,
    const float* __restrict__ s_src, const float* __restrict__ s_dst,
    const float* __restrict__ rdenom, float* __restrict__ att)
{
    const int e = blockIdx.x * 256 + threadIdx.x;
    if (e >= E_EDGES) return;
    const int s = src[e];
    const int d = dst[e];
    const float4* ps = (const float4*)(s_src + (size_t)s * HEADS);
    const float4* pd = (const float4*)(s_dst + (size_t)d * HEADS);
    const float4 s0 = ps[0], s1 = ps[1], d0 = pd[0], d1 = pd[1];
    const float4* pr = (const float4*)(rdenom + (size_t)s * HEADS);
    const float4 r0 = pr[0], r1 = pr[1];
    float sc[8] = {s0.x + d0.x, s0.y + d0.y, s0.z + d0.z, s0.w + d0.w,
                   s1.x + d1.x, s1.y + d1.y, s1.z + d1.z, s1.w + d1.w};
    float rd[8] = {r0.x, r0.y, r0.z, r0.w, r1.x, r1.y, r1.z, r1.w};
    float o[8];
#pragma unroll
    for (int h = 0; h < 8; h++) {
        float v = sc[h];
        v = v > 0.f ? v : SLOPE * v;
        o[h] = __expf(v) * rd[h];
    }
    float4* po = (float4*)(att + (size_t)e * HEADS);
    po[0] = make_float4(o[0], o[1], o[2], o[3]);
    po[1] = make_float4(o[4], o[5], o[6], o[7]);
}

extern "C" void kernel_launch(void* const* d_in, const int* in_sizes, int n_in,
                              void* d_out, int out_size, void* d_ws, size_t ws_size,
                              hipStream_t stream)
{
    const float* x    = (const float*)d_in[0];
    const int*   edge = (const int*)d_in[1];
    const float* W    = (const float*)d_in[2];
    const float* a    = (const float*)d_in[3];

    float* out = (float*)d_out;
    float* att = out;                                 // (E, HEADS)
    float* wx  = out + (size_t)E_EDGES * HEADS;       // (N, ATT)

    float* ws     = (float*)d_ws;
    float* s_src  = ws;                               // NH floats
    float* s_dst  = s_src + (size_t)NH;               // NH floats
    float* denoms = s_dst + (size_t)NH;               // NS * NH floats (25.6 MB)
    int*   counts = (int*)(denoms + (size_t)NS * NH); // NBINS*HB ints (229 KB)
    int*   offs   = counts + (size_t)NBINS * HB;      // NBINS*HB ints (229 KB)

    // binned[] lives in the att output region: it is fully consumed by
    // denom_binned_kernel before norm_kernel (the only att writer) runs.
    unsigned int* binned = (unsigned int*)att;        // E uints (12.8 MB)

    const int* src = edge;                 // edge[0][0][:]
    const int* dst = edge + E_EDGES;       // edge[0][1][:]

    const int gemm_blocks = (N_NODES + 127) / 128;    // 782
    gemm_s_kernel<<<gemm_blocks, 256, 0, stream>>>(x, W, a, wx, s_src, s_dst);

    hist_kernel<<<HB, 256, 0, stream>>>(src, counts);
    scan_kernel<<<1, 1024, 0, stream>>>(counts, offs);
    scatter_kernel<<<HB, 256, 0, stream>>>(src, dst, offs, binned);

    dim3 bgrid(NBINS, NS);                            // 112 x 8 = 896 blocks
    denom_binned_kernel<<<bgrid, 256, 0, stream>>>(binned, offs, s_src, s_dst, denoms);

    const int nblocks = (NH + 255) / 256;
    reduce_recip_kernel<<<nblocks, 256, 0, stream>>>(denoms);

    const int eblocks = (E_EDGES + 255) / 256;        // 12500
    norm_kernel<<<eblocks, 256, 0, stream>>>(src, dst, s_src, s_dst, denoms, att);
}